// Round 2
// baseline (265.949 us; speedup 1.0000x reference)
//
#include <hip/hip_runtime.h>
#include <cstdint>
#include <cstddef>

#define NB 4
#define NS 8192
#define ND 512
#define NP 1024
#define BK 32

typedef __bf16 bf16x8 __attribute__((ext_vector_type(8)));
typedef float f32x4 __attribute__((ext_vector_type(4)));

union FragU { uint4 u; bf16x8 h; };

__device__ __forceinline__ unsigned short bf16rne(float x) {
  unsigned int u = __builtin_bit_cast(unsigned int, x);
  u += 0x7FFFu + ((u >> 16) & 1u);
  return (unsigned short)(u >> 16);
}

__device__ __forceinline__ void gload16(const void* g, void* l) {
  __builtin_amdgcn_global_load_lds(
      (const __attribute__((address_space(1))) unsigned int*)g,
      (__attribute__((address_space(3))) unsigned int*)l, 16, 0, 0);
}

// ---------------------------------------------------------------------------
// Kernel A: Yt[b][p][s] = bf16( sqrt(w[b,s]) * (p<512 ? R[b,s,p] : I[b,s,p-512]) )
// LDS-tiled 64x64 transpose so both global read and write are coalesced.
// ---------------------------------------------------------------------------
__global__ __launch_bounds__(256)
void k_prep(const float* __restrict__ R, const float* __restrict__ I,
            const float* __restrict__ W, unsigned short* __restrict__ Yt) {
  __shared__ unsigned short L[64][66];   // pad 2 -> phase-2 gather ~conflict-free
  const int t   = threadIdx.x;
  const int blk = blockIdx.x;
  const int sb  = blk & 127;            // 128 s-blocks of 64
  const int pb  = (blk >> 7) & 15;      // 16 p-blocks of 64
  const int b   = blk >> 11;            // 4 batches
  const float* src = (pb < 8) ? R : I;
  const int col0 = (pb & 7) * 64;
  const int s0 = sb * 64;
  const int dl = (t & 15) * 4;
  const int sl0 = t >> 4;
#pragma unroll
  for (int r = 0; r < 4; ++r) {
    const int sl = sl0 + r * 16;
    const int s  = s0 + sl;
    const float sw = sqrtf(W[b * NS + s]);
    const float4 v = *(const float4*)(src + (size_t)(b * NS + s) * ND + col0 + dl);
    L[sl][dl + 0] = bf16rne(v.x * sw);
    L[sl][dl + 1] = bf16rne(v.y * sw);
    L[sl][dl + 2] = bf16rne(v.z * sw);
    L[sl][dl + 3] = bf16rne(v.w * sw);
  }
  __syncthreads();
  const int pl0 = t >> 3;               // 0..31
  const int sc  = (t & 7) * 8;          // 0..56
#pragma unroll
  for (int r = 0; r < 2; ++r) {
    const int pl = pl0 + r * 32;
    uint4 o;
    o.x = (unsigned)L[sc + 0][pl] | ((unsigned)L[sc + 1][pl] << 16);
    o.y = (unsigned)L[sc + 2][pl] | ((unsigned)L[sc + 3][pl] << 16);
    o.z = (unsigned)L[sc + 4][pl] | ((unsigned)L[sc + 5][pl] << 16);
    o.w = (unsigned)L[sc + 6][pl] | ((unsigned)L[sc + 7][pl] << 16);
    const int pg = pb * 64 + pl;
    *(uint4*)(Yt + (size_t)(b * NP + pg) * NS + (s0 + sc)) = o;
  }
}

// ---------------------------------------------------------------------------
// Kernel B: fused dual-output weighted-Gram GEMM.
// Block = 256 thr (4 waves, 2x2), 128x128 tile at (tm,tn), split-K partials
// (or direct f32 store to d_out when nsplit==1).
//   acc_r += ARᵀ·BR + AIᵀ·BI ;  acc_i += AIᵀ·BR − ARᵀ·BI
// LDS layout per tile (8 KiB): elem (m,k) at byte
//   (m>>1)*128 + ((64*(m&1) + 2k) ^ (((m>>1)&7)<<4))
// -> linear global_load_lds dest + inverse-swizzled SOURCE addresses;
//    frag ds_read_b128 and staging both bank-conflict-free.
// ---------------------------------------------------------------------------
__global__ __launch_bounds__(256, 2)
void k_gemm(const unsigned short* __restrict__ Yt, float* __restrict__ part,
            float* __restrict__ outp, int ksteps, int direct) {
  __shared__ uint4 lds4[2048];          // 32 KiB: AR 0 | AI 8192 | BR 16384 | BI 24576
  char* lds = (char*)lds4;
  const int bid   = blockIdx.x;
  const int pos   = bid & 15;
  const int b     = (bid >> 4) & 3;
  const int split = bid >> 6;
  const int tm = pos >> 2, tn = pos & 3;
  const int t = threadIdx.x;
  const int l = t & 63;
  const int w = t >> 6;

  // staging: lane's 16B chunk in linear LDS order maps to source (row, k-chunk)
  const int cj = l & 7;
  const int jj = l >> 3;
  const int ec = cj ^ jj;                       // swizzle: chunk ^ rowpair
  const int rbase = w * 16 + 2 * jj + (ec >> 2);
  const int colo  = (ec & 3) * 8;

  const int prow[4] = { tm * 128, 512 + tm * 128, tn * 128, 512 + tn * 128 };
  const unsigned short* gsrc[8];
#pragma unroll
  for (int tI = 0; tI < 4; ++tI)
#pragma unroll
    for (int i = 0; i < 2; ++i)
      gsrc[tI * 2 + i] = Yt + (size_t)(b * NP + prow[tI] + i * 64 + rbase) * NS
                         + (size_t)split * ((size_t)ksteps * BK) + colo;

  // per-lane fragment-read base (same for A and B tiles)
  const int g  = l >> 4;
  const int e_ = l & 1;
  const int q  = (l >> 1) & 7;
  const int ibase = ((l & 15) >> 1) * 128 + ((64 * e_ + 16 * g) ^ (q << 4));

  const int wm = w & 1, wn = w >> 1;
  const int mfb = wm * 4096;
  const int nfb = wn * 4096;

  f32x4 accr[4][4], acci[4][4];
  const f32x4 zz = {0.f, 0.f, 0.f, 0.f};
#pragma unroll
  for (int a = 0; a < 4; ++a)
#pragma unroll
    for (int c = 0; c < 4; ++c) { accr[a][c] = zz; acci[a][c] = zz; }

  for (int ks = 0; ks < ksteps; ++ks) {
#pragma unroll
    for (int u = 0; u < 8; ++u) {
      const int tI = u >> 1, ii = u & 1;
      gload16(gsrc[u], lds + tI * 8192 + ii * 4096 + w * 1024);
      gsrc[u] += BK;
    }
    __syncthreads();                    // drains vmcnt(0) before barrier
    FragU ar[4], ai[4];
#pragma unroll
    for (int mf = 0; mf < 4; ++mf) {
      ar[mf].u = *(const uint4*)(lds +         mfb + mf * 1024 + ibase);
      ai[mf].u = *(const uint4*)(lds + 8192  + mfb + mf * 1024 + ibase);
    }
#pragma unroll
    for (int nf = 0; nf < 4; ++nf) {
      FragU br, bi, bin;
      br.u = *(const uint4*)(lds + 16384 + nfb + nf * 1024 + ibase);
      bi.u = *(const uint4*)(lds + 24576 + nfb + nf * 1024 + ibase);
      bin.u.x = bi.u.x ^ 0x80008000u;
      bin.u.y = bi.u.y ^ 0x80008000u;
      bin.u.z = bi.u.z ^ 0x80008000u;
      bin.u.w = bi.u.w ^ 0x80008000u;
#pragma unroll
      for (int mf = 0; mf < 4; ++mf) {
        accr[mf][nf] = __builtin_amdgcn_mfma_f32_16x16x32_bf16(ar[mf].h, br.h,  accr[mf][nf], 0, 0, 0);
        accr[mf][nf] = __builtin_amdgcn_mfma_f32_16x16x32_bf16(ai[mf].h, bi.h,  accr[mf][nf], 0, 0, 0);
        acci[mf][nf] = __builtin_amdgcn_mfma_f32_16x16x32_bf16(ai[mf].h, br.h,  acci[mf][nf], 0, 0, 0);
        acci[mf][nf] = __builtin_amdgcn_mfma_f32_16x16x32_bf16(ar[mf].h, bin.h, acci[mf][nf], 0, 0, 0);
      }
    }
    __syncthreads();
  }

  const int lr = (l >> 4) * 4;
  const int lc = l & 15;
  if (direct) {
    // write straight to d_out: [o(2)][b(4)][512][512]
    const size_t ob = (size_t)b * 262144;
#pragma unroll
    for (int mf = 0; mf < 4; ++mf)
#pragma unroll
      for (int nf = 0; nf < 4; ++nf)
#pragma unroll
        for (int r = 0; r < 4; ++r) {
          const int row = tm * 128 + wm * 64 + mf * 16 + lr + r;
          const int col = tn * 128 + wn * 64 + nf * 16 + lc;
          outp[          ob + (size_t)row * 512 + col] = accr[mf][nf][r];
          outp[1048576 + ob + (size_t)row * 512 + col] = acci[mf][nf][r];
        }
  } else {
    // partial layout: [split][o(2)][b(4)][pos(16)][128][128] f32
    const size_t baser = ((size_t)(split * 2 + 0) * 4 + b) * (16 * 16384)
                         + (size_t)pos * 16384;
    const size_t basei = baser + (size_t)4 * 16 * 16384;
#pragma unroll
    for (int mf = 0; mf < 4; ++mf)
#pragma unroll
      for (int nf = 0; nf < 4; ++nf)
#pragma unroll
        for (int r = 0; r < 4; ++r) {
          const int mi = wm * 64 + mf * 16 + lr + r;
          const int ni = wn * 64 + nf * 16 + lc;
          part[baser + (size_t)mi * 128 + ni] = accr[mf][nf][r];
          part[basei + (size_t)mi * 128 + ni] = acci[mf][nf][r];
        }
  }
}

// ---------------------------------------------------------------------------
// Kernel C: sum split partials, scatter to d_out (out_r then out_i, [4,512,512]).
// ---------------------------------------------------------------------------
__global__ __launch_bounds__(256)
void k_reduce(const float* __restrict__ part, float* __restrict__ out, int nsplit) {
  const int tid = blockIdx.x * 256 + threadIdx.x;   // < 2097152
  float a = 0.f;
  for (int s = 0; s < nsplit; ++s)
    a += part[(size_t)s * 2097152 + tid];
  const int o    = tid >> 20;
  const int rem  = tid & 1048575;
  const int b    = rem >> 18;
  const int rem2 = rem & 262143;
  const int pos  = rem2 >> 14;
  const int e    = rem2 & 16383;
  const int tm = pos >> 2, tn = pos & 3;
  const int mi = e >> 7, ni = e & 127;
  out[(size_t)o * 1048576 + (size_t)b * 262144
      + (size_t)(tm * 128 + mi) * 512 + (tn * 128 + ni)] = a;
}

// ---------------------------------------------------------------------------
// Zero-workspace f32 fallback (only if ws_size < 64 MiB): LDS-tiled, sqrt(w)
// folded at stage time. Block computes a 32x32 (d,e) tile of out_r AND out_i
// for one batch. Slow (~2 ms) but safe and exact-ish (pure f32).
// ---------------------------------------------------------------------------
__global__ __launch_bounds__(256)
void k_fallback(const float* __restrict__ R, const float* __restrict__ I,
                const float* __restrict__ W, float* __restrict__ out) {
  __shared__ float Rd[64][32], Id[64][32], Re[64][32], Ie[64][32];
  const int blk = blockIdx.x;
  const int et = blk & 15, dt = (blk >> 4) & 15, b = blk >> 8;
  const int d0 = dt * 32, e0 = et * 32;
  const int t = threadIdx.x;
  const int dd = t >> 3;            // 0..31
  const int ee0 = (t & 7) * 4;      // 0..28
  float ar[4] = {0,0,0,0}, ai[4] = {0,0,0,0};
  for (int s0 = 0; s0 < NS; s0 += 64) {
#pragma unroll
    for (int k = 0; k < 8; ++k) {
      const int idx = t + k * 256;          // 0..2047
      const int row = idx >> 5, col = idx & 31;
      const float sw = sqrtf(W[b * NS + s0 + row]);
      const size_t gr = (size_t)(b * NS + s0 + row) * ND;
      Rd[row][col] = R[gr + d0 + col] * sw;
      Id[row][col] = I[gr + d0 + col] * sw;
      Re[row][col] = R[gr + e0 + col] * sw;
      Ie[row][col] = I[gr + e0 + col] * sw;
    }
    __syncthreads();
    for (int s = 0; s < 64; ++s) {
      const float rd = Rd[s][dd], id = Id[s][dd];
#pragma unroll
      for (int j = 0; j < 4; ++j) {
        const float re = Re[s][ee0 + j], ie = Ie[s][ee0 + j];
        ar[j] += rd * re + id * ie;
        ai[j] += id * re - rd * ie;
      }
    }
    __syncthreads();
  }
  const size_t ob = (size_t)b * 262144;
#pragma unroll
  for (int j = 0; j < 4; ++j) {
    out[          ob + (size_t)(d0 + dd) * 512 + e0 + ee0 + j] = ar[j];
    out[1048576 + ob + (size_t)(d0 + dd) * 512 + e0 + ee0 + j] = ai[j];
  }
}

extern "C" void kernel_launch(void* const* d_in, const int* in_sizes, int n_in,
                              void* d_out, int out_size, void* d_ws, size_t ws_size,
                              hipStream_t stream) {
  const float* R = (const float*)d_in[0];
  const float* I = (const float*)d_in[1];
  const float* W = (const float*)d_in[2];
  float* out = (float*)d_out;
  const size_t ytBytes  = (size_t)NB * NP * NS * 2;         // 64 MiB
  const size_t perSplit = (size_t)2 * NB * 16 * 16384 * 4;  // 8 MiB / split

  if (ws_size < ytBytes) {
    // workspace too small for the MFMA path -> safe slow fallback, no ws use
    k_fallback<<<dim3(NB * 16 * 16), dim3(256), 0, stream>>>(R, I, W, out);
    return;
  }

  unsigned short* Yt = (unsigned short*)d_ws;
  float* part = (float*)((char*)d_ws + ytBytes);
  int SPLIT = 8;
  while (SPLIT > 1 && ytBytes + (size_t)SPLIT * perSplit > ws_size) SPLIT >>= 1;

  k_prep<<<dim3(NB * 16 * 128), dim3(256), 0, stream>>>(R, I, W, Yt);
  if (SPLIT > 1) {
    k_gemm<<<dim3(64 * SPLIT), dim3(256), 0, stream>>>(Yt, part, nullptr,
                                                       256 / SPLIT, 0);
    k_reduce<<<dim3(8192), dim3(256), 0, stream>>>(part, out, SPLIT);
  } else {
    k_gemm<<<dim3(64), dim3(256), 0, stream>>>(Yt, nullptr, out, 256, 1);
  }
}

// Round 3
// 246.820 us; speedup vs baseline: 1.0775x; 1.0775x over previous
//
#include <hip/hip_runtime.h>
#include <cstdint>
#include <cstddef>

#define NB 4
#define NS 8192
#define ND 512
#define NP 1024
#define BK 32

typedef __bf16 bf16x8 __attribute__((ext_vector_type(8)));
typedef float f32x4 __attribute__((ext_vector_type(4)));

union FragU { uint4 u; bf16x8 h; };

__device__ __forceinline__ unsigned short bf16rne(float x) {
  unsigned int u = __builtin_bit_cast(unsigned int, x);
  u += 0x7FFFu + ((u >> 16) & 1u);
  return (unsigned short)(u >> 16);
}

__device__ __forceinline__ void gload16(const void* g, void* l) {
  __builtin_amdgcn_global_load_lds(
      (const __attribute__((address_space(1))) unsigned int*)g,
      (__attribute__((address_space(3))) unsigned int*)l, 16, 0, 0);
}

// ---------------------------------------------------------------------------
// Kernel A: Yt[b][p][s] = bf16( sqrt(w[b,s]) * (p<512 ? R[b,s,p] : I[b,s,p-512]) )
// LDS-tiled 64x64 transpose so both global read and write are coalesced.
// ---------------------------------------------------------------------------
__global__ __launch_bounds__(256)
void k_prep(const float* __restrict__ R, const float* __restrict__ I,
            const float* __restrict__ W, unsigned short* __restrict__ Yt) {
  __shared__ unsigned short L[64][66];
  const int t   = threadIdx.x;
  const int blk = blockIdx.x;
  const int sb  = blk & 127;
  const int pb  = (blk >> 7) & 15;
  const int b   = blk >> 11;
  const float* src = (pb < 8) ? R : I;
  const int col0 = (pb & 7) * 64;
  const int s0 = sb * 64;
  const int dl = (t & 15) * 4;
  const int sl0 = t >> 4;
#pragma unroll
  for (int r = 0; r < 4; ++r) {
    const int sl = sl0 + r * 16;
    const int s  = s0 + sl;
    const float sw = sqrtf(W[b * NS + s]);
    const float4 v = *(const float4*)(src + (size_t)(b * NS + s) * ND + col0 + dl);
    L[sl][dl + 0] = bf16rne(v.x * sw);
    L[sl][dl + 1] = bf16rne(v.y * sw);
    L[sl][dl + 2] = bf16rne(v.z * sw);
    L[sl][dl + 3] = bf16rne(v.w * sw);
  }
  __syncthreads();
  const int pl0 = t >> 3;
  const int sc  = (t & 7) * 8;
#pragma unroll
  for (int r = 0; r < 2; ++r) {
    const int pl = pl0 + r * 32;
    uint4 o;
    o.x = (unsigned)L[sc + 0][pl] | ((unsigned)L[sc + 1][pl] << 16);
    o.y = (unsigned)L[sc + 2][pl] | ((unsigned)L[sc + 3][pl] << 16);
    o.z = (unsigned)L[sc + 4][pl] | ((unsigned)L[sc + 5][pl] << 16);
    o.w = (unsigned)L[sc + 6][pl] | ((unsigned)L[sc + 7][pl] << 16);
    const int pg = pb * 64 + pl;
    *(uint4*)(Yt + (size_t)(b * NP + pg) * NS + (s0 + sc)) = o;
  }
}

// ---------------------------------------------------------------------------
// Kernel B: fused dual-output weighted-Gram GEMM, SYMMETRIC (tm>=tn tiles
// only: out_r symmetric, out_i antisymmetric) + double-buffered 2-phase
// (stage next K-step during compute; ONE barrier per K-step).
// Block = 256 thr (4 waves 2x2), 128x128 tile, split-K partials.
//   acc_r += ARt*BR + AIt*BI ;  acc_i += AIt*BR - ARt*BI
// LDS per buf (32 KiB): AR 0 | AI 8K | BR 16K | BI 24K; 2 bufs = 64 KiB.
// Swizzle: elem (m,k) at byte (m>>1)*128 + ((64*(m&1)+2k) ^ (((m>>1)&7)<<4));
// linear gload_lds dest + inverse-swizzled global src; all reads conflict-free
// (verified: SQ_LDS_BANK_CONFLICT == 0 in round 2).
// ---------------------------------------------------------------------------
__global__ __launch_bounds__(256, 2)
void k_gemm(const unsigned short* __restrict__ Yt, float* __restrict__ part,
            int ksteps) {
  __shared__ uint4 lds4[4096];          // 64 KiB (2 x 32 KiB bufs)
  char* lds = (char*)lds4;
  static const int TMp[10] = {0,1,1,2,2,2,3,3,3,3};
  static const int TNp[10] = {0,0,1,0,1,2,0,1,2,3};
  const int bid   = blockIdx.x;
  const int pos40 = bid % 40;
  const int split = bid / 40;
  const int b     = pos40 / 10;
  const int p     = pos40 % 10;
  const int tm = TMp[p], tn = TNp[p];
  const int t = threadIdx.x;
  const int l = t & 63;
  const int w = t >> 6;

  // staging: lane's 16B chunk in linear LDS order -> inverse-swizzled source
  const int cj = l & 7;
  const int jj = l >> 3;
  const int ec = cj ^ jj;
  const int rbase = w * 16 + 2 * jj + (ec >> 2);
  const int colo  = (ec & 3) * 8;

  const int prow[4] = { tm * 128, 512 + tm * 128, tn * 128, 512 + tn * 128 };
  const unsigned short* gsrc[8];
  int dstoff[8];
#pragma unroll
  for (int tI = 0; tI < 4; ++tI)
#pragma unroll
    for (int i = 0; i < 2; ++i) {
      gsrc[tI * 2 + i] = Yt + (size_t)(b * NP + prow[tI] + i * 64 + rbase) * NS
                         + (size_t)split * ((size_t)ksteps * BK) + colo;
      dstoff[tI * 2 + i] = tI * 8192 + i * 4096 + w * 1024;
    }

  // per-lane fragment-read base
  const int g  = l >> 4;
  const int e_ = l & 1;
  const int q  = (l >> 1) & 7;
  const int ibase = ((l & 15) >> 1) * 128 + ((64 * e_ + 16 * g) ^ (q << 4));

  const int wm = w & 1, wn = w >> 1;
  const int mfb = wm * 4096;
  const int nfb = wn * 4096;

  f32x4 accr[4][4], acci[4][4];
  const f32x4 zz = {0.f, 0.f, 0.f, 0.f};
#pragma unroll
  for (int a = 0; a < 4; ++a)
#pragma unroll
    for (int c = 0; c < 4; ++c) { accr[a][c] = zz; acci[a][c] = zz; }

  // prologue: stage K-step 0 into buf 0
#pragma unroll
  for (int u = 0; u < 8; ++u) { gload16(gsrc[u], lds + dstoff[u]); gsrc[u] += BK; }
  __syncthreads();

  int cur = 0;
  for (int ks = 0; ks < ksteps; ++ks) {
    const int cbase = cur * 32768;
    const int nbase = cbase ^ 32768;
    if (ks + 1 < ksteps) {              // stage next step into other buf
#pragma unroll
      for (int u = 0; u < 8; ++u) { gload16(gsrc[u], lds + nbase + dstoff[u]); gsrc[u] += BK; }
    }
    FragU ar[4], ai[4];
#pragma unroll
    for (int mf = 0; mf < 4; ++mf) {
      ar[mf].u = *(const uint4*)(lds + cbase +        mfb + mf * 1024 + ibase);
      ai[mf].u = *(const uint4*)(lds + cbase + 8192 + mfb + mf * 1024 + ibase);
    }
#pragma unroll
    for (int nf = 0; nf < 4; ++nf) {
      FragU br, bi, bin;
      br.u = *(const uint4*)(lds + cbase + 16384 + nfb + nf * 1024 + ibase);
      bi.u = *(const uint4*)(lds + cbase + 24576 + nfb + nf * 1024 + ibase);
      bin.u.x = bi.u.x ^ 0x80008000u;
      bin.u.y = bi.u.y ^ 0x80008000u;
      bin.u.z = bi.u.z ^ 0x80008000u;
      bin.u.w = bi.u.w ^ 0x80008000u;
#pragma unroll
      for (int mf = 0; mf < 4; ++mf) {
        accr[mf][nf] = __builtin_amdgcn_mfma_f32_16x16x32_bf16(ar[mf].h, br.h,  accr[mf][nf], 0, 0, 0);
        accr[mf][nf] = __builtin_amdgcn_mfma_f32_16x16x32_bf16(ai[mf].h, bi.h,  accr[mf][nf], 0, 0, 0);
        acci[mf][nf] = __builtin_amdgcn_mfma_f32_16x16x32_bf16(ai[mf].h, br.h,  acci[mf][nf], 0, 0, 0);
        acci[mf][nf] = __builtin_amdgcn_mfma_f32_16x16x32_bf16(ar[mf].h, bin.h, acci[mf][nf], 0, 0, 0);
      }
    }
    __syncthreads();                    // drains staging vmcnt + LDS reads
    cur ^= 1;
  }

  // partial layout: [split][b*10+p][o(2)][128][128] f32
  const size_t baser = ((size_t)(split * 40 + pos40) * 2 + 0) * 16384;
  const size_t basei = baser + 16384;
  const int lr = (l >> 4) * 4;
  const int lc = l & 15;
#pragma unroll
  for (int mf = 0; mf < 4; ++mf)
#pragma unroll
    for (int nf = 0; nf < 4; ++nf)
#pragma unroll
      for (int r = 0; r < 4; ++r) {
        const int mi = wm * 64 + mf * 16 + lr + r;
        const int ni = wn * 64 + nf * 16 + lc;
        part[baser + (size_t)mi * 128 + ni] = accr[mf][nf][r];
        part[basei + (size_t)mi * 128 + ni] = acci[mf][nf][r];
      }
}

// ---------------------------------------------------------------------------
// Kernel C: sum split partials, write the LOWER (tm>=tn) tiles of d_out.
// ---------------------------------------------------------------------------
__global__ __launch_bounds__(256)
void k_reduce(const float* __restrict__ part, float* __restrict__ out, int nsplit) {
  static const int TMp[10] = {0,1,1,2,2,2,3,3,3,3};
  static const int TNp[10] = {0,0,1,0,1,2,0,1,2,3};
  const int idx = blockIdx.x * 256 + threadIdx.x;   // < 1310720
  const int ni = idx & 127;
  const int mi = (idx >> 7) & 127;
  const int o  = (idx >> 14) & 1;
  const int bp = idx >> 15;                         // 0..39
  const int b = bp / 10, p = bp % 10;
  const size_t stride = (size_t)40 * 2 * 16384;
  size_t base = ((size_t)bp * 2 + o) * 16384 + (size_t)mi * 128 + ni;
  float a = 0.f;
  for (int s = 0; s < nsplit; ++s)
    a += part[base + (size_t)s * stride];
  const int d = TMp[p] * 128 + mi;
  const int e = TNp[p] * 128 + ni;
  out[(size_t)o * 1048576 + (size_t)b * 262144 + (size_t)d * 512 + e] = a;
}

// ---------------------------------------------------------------------------
// Kernel D: mirror upper tiles from the (already-written, L2-hot) lower tiles.
// out_r[d,e] = out_r[e,d]; out_i[d,e] = -out_i[e,d]. LDS 64x64 transpose,
// coalesced float4 both directions.
// ---------------------------------------------------------------------------
__global__ __launch_bounds__(256)
void k_mirror(float* __restrict__ out) {
  __shared__ float T[64][65];
  static const int UM[6] = {0,0,0,1,1,2};
  static const int UN[6] = {1,2,3,2,3,3};
  const int m = blockIdx.x;               // 192 = 6u * 2o * 4b * 4sub
  const int sub = m & 3;
  const int b   = (m >> 2) & 3;
  const int o   = (m >> 4) & 1;
  const int u   = m >> 5;
  const int d0 = UM[u] * 128 + (sub & 1) * 64;
  const int e0 = UN[u] * 128 + ((sub >> 1) & 1) * 64;
  const float sign = o ? -1.f : 1.f;
  float* base = out + (size_t)o * 1048576 + (size_t)b * 262144;
  const int t  = threadIdx.x;
  const int c4 = (t & 15) * 4;
  const int r0 = t >> 4;                  // 0..15
#pragma unroll
  for (int i = 0; i < 4; ++i) {
    const int r = r0 + i * 16;
    const float4 v = *(const float4*)(base + (size_t)(e0 + r) * 512 + d0 + c4);
    T[c4 + 0][r] = v.x; T[c4 + 1][r] = v.y;
    T[c4 + 2][r] = v.z; T[c4 + 3][r] = v.w;
  }
  __syncthreads();
#pragma unroll
  for (int i = 0; i < 4; ++i) {
    const int r = r0 + i * 16;
    float4 wv;
    wv.x = sign * T[r][c4 + 0]; wv.y = sign * T[r][c4 + 1];
    wv.z = sign * T[r][c4 + 2]; wv.w = sign * T[r][c4 + 3];
    *(float4*)(base + (size_t)(d0 + r) * 512 + e0 + c4) = wv;
  }
}

// ---------------------------------------------------------------------------
// Zero-workspace f32 fallback (only if ws too small). Safe, slow.
// ---------------------------------------------------------------------------
__global__ __launch_bounds__(256)
void k_fallback(const float* __restrict__ R, const float* __restrict__ I,
                const float* __restrict__ W, float* __restrict__ out) {
  __shared__ float Rd[64][32], Id[64][32], Re[64][32], Ie[64][32];
  const int blk = blockIdx.x;
  const int et = blk & 15, dt = (blk >> 4) & 15, b = blk >> 8;
  const int d0 = dt * 32, e0 = et * 32;
  const int t = threadIdx.x;
  const int dd = t >> 3;
  const int ee0 = (t & 7) * 4;
  float ar[4] = {0,0,0,0}, ai[4] = {0,0,0,0};
  for (int s0 = 0; s0 < NS; s0 += 64) {
#pragma unroll
    for (int k = 0; k < 8; ++k) {
      const int idx = t + k * 256;
      const int row = idx >> 5, col = idx & 31;
      const float sw = sqrtf(W[b * NS + s0 + row]);
      const size_t gr = (size_t)(b * NS + s0 + row) * ND;
      Rd[row][col] = R[gr + d0 + col] * sw;
      Id[row][col] = I[gr + d0 + col] * sw;
      Re[row][col] = R[gr + e0 + col] * sw;
      Ie[row][col] = I[gr + e0 + col] * sw;
    }
    __syncthreads();
    for (int s = 0; s < 64; ++s) {
      const float rd = Rd[s][dd], id = Id[s][dd];
#pragma unroll
      for (int j = 0; j < 4; ++j) {
        const float re = Re[s][ee0 + j], ie = Ie[s][ee0 + j];
        ar[j] += rd * re + id * ie;
        ai[j] += id * re - rd * ie;
      }
    }
    __syncthreads();
  }
  const size_t ob = (size_t)b * 262144;
#pragma unroll
  for (int j = 0; j < 4; ++j) {
    out[          ob + (size_t)(d0 + dd) * 512 + e0 + ee0 + j] = ar[j];
    out[1048576 + ob + (size_t)(d0 + dd) * 512 + e0 + ee0 + j] = ai[j];
  }
}

extern "C" void kernel_launch(void* const* d_in, const int* in_sizes, int n_in,
                              void* d_out, int out_size, void* d_ws, size_t ws_size,
                              hipStream_t stream) {
  const float* R = (const float*)d_in[0];
  const float* I = (const float*)d_in[1];
  const float* W = (const float*)d_in[2];
  float* out = (float*)d_out;
  const size_t ytBytes  = (size_t)NB * NP * NS * 2;        // 64 MiB
  const size_t perSplit = (size_t)40 * 2 * 16384 * 4;      // 5.24 MB / split

  int SPLIT = 16;
  while (SPLIT > 2 && ytBytes + (size_t)SPLIT * perSplit > ws_size) SPLIT >>= 1;
  if (ytBytes + (size_t)SPLIT * perSplit > ws_size) {
    k_fallback<<<dim3(NB * 16 * 16), dim3(256), 0, stream>>>(R, I, W, out);
    return;
  }

  unsigned short* Yt = (unsigned short*)d_ws;
  float* part = (float*)((char*)d_ws + ytBytes);

  k_prep<<<dim3(NB * 16 * 128), dim3(256), 0, stream>>>(R, I, W, Yt);
  k_gemm<<<dim3(40 * SPLIT), dim3(256), 0, stream>>>(Yt, part, 256 / SPLIT);
  k_reduce<<<dim3(5120), dim3(256), 0, stream>>>(part, out, SPLIT);
  k_mirror<<<dim3(192), dim3(256), 0, stream>>>(out);
}

// Round 4
// 234.338 us; speedup vs baseline: 1.1349x; 1.0533x over previous
//
#include <hip/hip_runtime.h>
#include <cstdint>
#include <cstddef>

#define NB 4
#define NS 8192
#define ND 512
#define NP 1024
#define BK 32

typedef __bf16 bf16x8 __attribute__((ext_vector_type(8)));
typedef float f32x4 __attribute__((ext_vector_type(4)));

union FragU { uint4 u; bf16x8 h; };

__device__ __forceinline__ unsigned short bf16rne(float x) {
  unsigned int u = __builtin_bit_cast(unsigned int, x);
  u += 0x7FFFu + ((u >> 16) & 1u);
  return (unsigned short)(u >> 16);
}

__device__ __forceinline__ void gload16(const void* g, void* l) {
  __builtin_amdgcn_global_load_lds(
      (const __attribute__((address_space(1))) unsigned int*)g,
      (__attribute__((address_space(3))) unsigned int*)l, 16, 0, 0);
}

// ---------------------------------------------------------------------------
// Kernel A: Yt[b][p][s] = bf16( sqrt(w[b,s]) * (p<512 ? R[b,s,p] : I[b,s,p-512]) )
// ---------------------------------------------------------------------------
__global__ __launch_bounds__(256)
void k_prep(const float* __restrict__ R, const float* __restrict__ I,
            const float* __restrict__ W, unsigned short* __restrict__ Yt) {
  __shared__ unsigned short L[64][66];
  const int t   = threadIdx.x;
  const int blk = blockIdx.x;
  const int sb  = blk & 127;
  const int pb  = (blk >> 7) & 15;
  const int b   = blk >> 11;
  const float* src = (pb < 8) ? R : I;
  const int col0 = (pb & 7) * 64;
  const int s0 = sb * 64;
  const int dl = (t & 15) * 4;
  const int sl0 = t >> 4;
#pragma unroll
  for (int r = 0; r < 4; ++r) {
    const int sl = sl0 + r * 16;
    const int s  = s0 + sl;
    const float sw = sqrtf(W[b * NS + s]);
    const float4 v = *(const float4*)(src + (size_t)(b * NS + s) * ND + col0 + dl);
    L[sl][dl + 0] = bf16rne(v.x * sw);
    L[sl][dl + 1] = bf16rne(v.y * sw);
    L[sl][dl + 2] = bf16rne(v.z * sw);
    L[sl][dl + 3] = bf16rne(v.w * sw);
  }
  __syncthreads();
  const int pl0 = t >> 3;
  const int sc  = (t & 7) * 8;
#pragma unroll
  for (int r = 0; r < 2; ++r) {
    const int pl = pl0 + r * 32;
    uint4 o;
    o.x = (unsigned)L[sc + 0][pl] | ((unsigned)L[sc + 1][pl] << 16);
    o.y = (unsigned)L[sc + 2][pl] | ((unsigned)L[sc + 3][pl] << 16);
    o.z = (unsigned)L[sc + 4][pl] | ((unsigned)L[sc + 5][pl] << 16);
    o.w = (unsigned)L[sc + 6][pl] | ((unsigned)L[sc + 7][pl] << 16);
    const int pg = pb * 64 + pl;
    *(uint4*)(Yt + (size_t)(b * NP + pg) * NS + (s0 + sc)) = o;
  }
}

// ---------------------------------------------------------------------------
// Kernel B: fused dual-output symmetric weighted-Gram GEMM.
// Flat-balanced: 512 blocks x exactly 20 K-steps over the 40*256 global step
// space (2.0 blocks/CU, zero quantization). A block covers <=2 (pos,K) segs;
// seg0 partial -> slot j, seg1 (straddle) -> slot 512+pos (unique per pos).
// Pipeline (T3/T4): dbuf 2x32KiB, counted s_waitcnt vmcnt(8) -> loads stay in
// flight across raw s_barrier; two barriers/step; vmcnt(0) only at prologue /
// last step. T5 setprio around the 64-MFMA cluster.
// Swizzle (verified conflict-free, rounds 2-3): elem (m,k) of a panel at byte
// (m>>1)*128 + ((64*(m&1)+2k) ^ (((m>>1)&7)<<4)); linear gload_lds dest +
// inverse-swizzled global source.
// ---------------------------------------------------------------------------
__global__ __launch_bounds__(256, 2)
void k_gemm(const unsigned short* __restrict__ Yt, float* __restrict__ part) {
  __shared__ uint4 lds4[4096];          // 64 KiB = 2 bufs x (AR|AI|BR|BI)
  char* lds = (char*)lds4;
  static const int TMp[10] = {0,1,1,2,2,2,3,3,3,3};
  static const int TNp[10] = {0,0,1,0,1,2,0,1,2,3};
  const int j  = blockIdx.x;            // 0..511
  const int g0 = j * 20;
  const int g1 = g0 + 20;
  const int p0 = g0 >> 8;
  const int p1 = (g1 - 1) >> 8;
  const int t = threadIdx.x;
  const int l = t & 63, w = t >> 6;

  // staging lane geometry: linear LDS dest chunk -> inverse-swizzled source
  const int cj = l & 7, jj = l >> 3;
  const int ec = cj ^ jj;
  const int rbase = w * 16 + 2 * jj + (ec >> 2);
  const int colo  = (ec & 3) * 8;
  int dstoff[8];
#pragma unroll
  for (int u = 0; u < 8; ++u) dstoff[u] = (u >> 1) * 8192 + (u & 1) * 4096 + w * 1024;

  // fragment-read base
  const int gfr = l >> 4, e_ = l & 1, q = (l >> 1) & 7;
  const int ibase = ((l & 15) >> 1) * 128 + ((64 * e_ + 16 * gfr) ^ (q << 4));
  const int wm = w & 1, wn = w >> 1;
  const int mfb = wm * 4096, nfb = wn * 4096;
  const int lr = (l >> 4) * 4, lc = l & 15;

  for (int seg = 0; seg < 2; ++seg) {
    int pos, k0, ns;
    if (seg == 0) {
      pos = p0; k0 = g0 & 255;
      ns = 256 - k0; if (ns > 20) ns = 20;
    } else {
      if (p1 == p0) break;
      pos = p1; k0 = 0; ns = g1 & 255;  // in (0,20)
    }
    const int b = pos / 10, p = pos % 10;
    const int tm = TMp[p], tn = TNp[p];
    const int prow[4] = { tm * 128, 512 + tm * 128, tn * 128, 512 + tn * 128 };
    const unsigned short* gsrc[8];
#pragma unroll
    for (int u = 0; u < 8; ++u)
      gsrc[u] = Yt + (size_t)(b * NP + prow[u >> 1] + (u & 1) * 64 + rbase) * NS
                + (size_t)k0 * BK + colo;

    f32x4 accr[4][4], acci[4][4];
    const f32x4 zz = {0.f, 0.f, 0.f, 0.f};
#pragma unroll
    for (int a = 0; a < 4; ++a)
#pragma unroll
      for (int c = 0; c < 4; ++c) { accr[a][c] = zz; acci[a][c] = zz; }

    // prologue: stage step 0 into buf0, full drain
#pragma unroll
    for (int u = 0; u < 8; ++u) { gload16(gsrc[u], lds + dstoff[u]); gsrc[u] += BK; }
    __builtin_amdgcn_sched_barrier(0);
    asm volatile("s_waitcnt vmcnt(0)" ::: "memory");
    __builtin_amdgcn_s_barrier();

    int cur = 0;
    for (int ks = 0; ks < ns; ++ks) {
      const int cbase = cur * 32768;
      if (ks + 1 < ns) {
        const int nbase = cbase ^ 32768;
#pragma unroll
        for (int u = 0; u < 8; ++u) { gload16(gsrc[u], lds + nbase + dstoff[u]); gsrc[u] += BK; }
        __builtin_amdgcn_sched_barrier(0);
        asm volatile("s_waitcnt vmcnt(8)" ::: "memory");  // cur's 8 landed; nxt's 8 fly
      } else {
        asm volatile("s_waitcnt vmcnt(0)" ::: "memory");
      }
      __builtin_amdgcn_s_barrier();     // barrier1: all waves' cur staging visible

      FragU ar[4], ai[4];
#pragma unroll
      for (int mf = 0; mf < 4; ++mf) {
        ar[mf].u = *(const uint4*)(lds + cbase +        mfb + mf * 1024 + ibase);
        ai[mf].u = *(const uint4*)(lds + cbase + 8192 + mfb + mf * 1024 + ibase);
      }
      __builtin_amdgcn_s_setprio(1);
#pragma unroll
      for (int nf = 0; nf < 4; ++nf) {
        FragU br, bi, bin;
        br.u = *(const uint4*)(lds + cbase + 16384 + nfb + nf * 1024 + ibase);
        bi.u = *(const uint4*)(lds + cbase + 24576 + nfb + nf * 1024 + ibase);
        bin.u.x = bi.u.x ^ 0x80008000u;
        bin.u.y = bi.u.y ^ 0x80008000u;
        bin.u.z = bi.u.z ^ 0x80008000u;
        bin.u.w = bi.u.w ^ 0x80008000u;
#pragma unroll
        for (int mf = 0; mf < 4; ++mf) {
          accr[mf][nf] = __builtin_amdgcn_mfma_f32_16x16x32_bf16(ar[mf].h, br.h,  accr[mf][nf], 0, 0, 0);
          accr[mf][nf] = __builtin_amdgcn_mfma_f32_16x16x32_bf16(ai[mf].h, bi.h,  accr[mf][nf], 0, 0, 0);
          acci[mf][nf] = __builtin_amdgcn_mfma_f32_16x16x32_bf16(ai[mf].h, br.h,  acci[mf][nf], 0, 0, 0);
          acci[mf][nf] = __builtin_amdgcn_mfma_f32_16x16x32_bf16(ar[mf].h, bin.h, acci[mf][nf], 0, 0, 0);
        }
      }
      __builtin_amdgcn_s_setprio(0);
      __builtin_amdgcn_s_barrier();     // barrier2: reads done -> buf reusable
      cur ^= 1;
    }

    // segment epilogue: partial slot = (seg==0 ? j : 512+pos), [slot][o][128][128]
    const int slot = (seg == 0) ? j : (512 + pos);
    const size_t baser = (size_t)slot * 32768;
    const size_t basei = baser + 16384;
#pragma unroll
    for (int mf = 0; mf < 4; ++mf)
#pragma unroll
      for (int nf = 0; nf < 4; ++nf)
#pragma unroll
        for (int r = 0; r < 4; ++r) {
          const int mi = wm * 64 + mf * 16 + lr + r;
          const int ni = wn * 64 + nf * 16 + lc;
          part[baser + (size_t)mi * 128 + ni] = accr[mf][nf][r];
          part[basei + (size_t)mi * 128 + ni] = acci[mf][nf][r];
        }
  }
}

// ---------------------------------------------------------------------------
// Kernel C: sum contributing partial slots per position, write lower tiles.
// For pos P: primary blocks j in [ceil(256P/20), floor((256P+255)/20)] plus
// straddler slot 512+P iff 256P % 20 != 0.
// ---------------------------------------------------------------------------
__global__ __launch_bounds__(256)
void k_reduce(const float* __restrict__ part, float* __restrict__ out) {
  static const int TMp[10] = {0,1,1,2,2,2,3,3,3,3};
  static const int TNp[10] = {0,0,1,0,1,2,0,1,2,3};
  const int idx = blockIdx.x * 256 + threadIdx.x;   // < 1310720
  const int ni = idx & 127;
  const int mi = (idx >> 7) & 127;
  const int o  = (idx >> 14) & 1;
  const int P  = idx >> 15;                         // 0..39
  const int jlo = (256 * P + 19) / 20;
  const int jhi = (256 * P + 255) / 20;
  const size_t off = (size_t)o * 16384 + (size_t)mi * 128 + ni;
  float a = 0.f;
  for (int s = jlo; s <= jhi; ++s)
    a += part[(size_t)s * 32768 + off];
  if ((256 * P) % 20)
    a += part[(size_t)(512 + P) * 32768 + off];
  const int b = P / 10, p = P % 10;
  const int d = TMp[p] * 128 + mi;
  const int e = TNp[p] * 128 + ni;
  out[(size_t)o * 1048576 + (size_t)b * 262144 + (size_t)d * 512 + e] = a;
}

// ---------------------------------------------------------------------------
// Kernel D: mirror upper tiles (out_r symmetric, out_i antisymmetric).
// ---------------------------------------------------------------------------
__global__ __launch_bounds__(256)
void k_mirror(float* __restrict__ out) {
  __shared__ float T[64][65];
  static const int UM[6] = {0,0,0,1,1,2};
  static const int UN[6] = {1,2,3,2,3,3};
  const int m = blockIdx.x;               // 192
  const int sub = m & 3;
  const int b   = (m >> 2) & 3;
  const int o   = (m >> 4) & 1;
  const int u   = m >> 5;
  const int d0 = UM[u] * 128 + (sub & 1) * 64;
  const int e0 = UN[u] * 128 + ((sub >> 1) & 1) * 64;
  const float sign = o ? -1.f : 1.f;
  float* base = out + (size_t)o * 1048576 + (size_t)b * 262144;
  const int t  = threadIdx.x;
  const int c4 = (t & 15) * 4;
  const int r0 = t >> 4;
#pragma unroll
  for (int i = 0; i < 4; ++i) {
    const int r = r0 + i * 16;
    const float4 v = *(const float4*)(base + (size_t)(e0 + r) * 512 + d0 + c4);
    T[c4 + 0][r] = v.x; T[c4 + 1][r] = v.y;
    T[c4 + 2][r] = v.z; T[c4 + 3][r] = v.w;
  }
  __syncthreads();
#pragma unroll
  for (int i = 0; i < 4; ++i) {
    const int r = r0 + i * 16;
    float4 wv;
    wv.x = sign * T[r][c4 + 0]; wv.y = sign * T[r][c4 + 1];
    wv.z = sign * T[r][c4 + 2]; wv.w = sign * T[r][c4 + 3];
    *(float4*)(base + (size_t)(d0 + r) * 512 + e0 + c4) = wv;
  }
}

// ---------------------------------------------------------------------------
// Zero-workspace f32 fallback (ws too small). Safe, slow.
// ---------------------------------------------------------------------------
__global__ __launch_bounds__(256)
void k_fallback(const float* __restrict__ R, const float* __restrict__ I,
                const float* __restrict__ W, float* __restrict__ out) {
  __shared__ float Rd[64][32], Id[64][32], Re[64][32], Ie[64][32];
  const int blk = blockIdx.x;
  const int et = blk & 15, dt = (blk >> 4) & 15, b = blk >> 8;
  const int d0 = dt * 32, e0 = et * 32;
  const int t = threadIdx.x;
  const int dd = t >> 3;
  const int ee0 = (t & 7) * 4;
  float ar[4] = {0,0,0,0}, ai[4] = {0,0,0,0};
  for (int s0 = 0; s0 < NS; s0 += 64) {
#pragma unroll
    for (int k = 0; k < 8; ++k) {
      const int idx = t + k * 256;
      const int row = idx >> 5, col = idx & 31;
      const float sw = sqrtf(W[b * NS + s0 + row]);
      const size_t gr = (size_t)(b * NS + s0 + row) * ND;
      Rd[row][col] = R[gr + d0 + col] * sw;
      Id[row][col] = I[gr + d0 + col] * sw;
      Re[row][col] = R[gr + e0 + col] * sw;
      Ie[row][col] = I[gr + e0 + col] * sw;
    }
    __syncthreads();
    for (int s = 0; s < 64; ++s) {
      const float rd = Rd[s][dd], id = Id[s][dd];
#pragma unroll
      for (int jx = 0; jx < 4; ++jx) {
        const float re = Re[s][ee0 + jx], ie = Ie[s][ee0 + jx];
        ar[jx] += rd * re + id * ie;
        ai[jx] += id * re - rd * ie;
      }
    }
    __syncthreads();
  }
  const size_t ob = (size_t)b * 262144;
#pragma unroll
  for (int jx = 0; jx < 4; ++jx) {
    out[          ob + (size_t)(d0 + dd) * 512 + e0 + ee0 + jx] = ar[jx];
    out[1048576 + ob + (size_t)(d0 + dd) * 512 + e0 + ee0 + jx] = ai[jx];
  }
}

extern "C" void kernel_launch(void* const* d_in, const int* in_sizes, int n_in,
                              void* d_out, int out_size, void* d_ws, size_t ws_size,
                              hipStream_t stream) {
  const float* R = (const float*)d_in[0];
  const float* I = (const float*)d_in[1];
  const float* W = (const float*)d_in[2];
  float* out = (float*)d_out;
  const size_t ytBytes   = (size_t)NB * NP * NS * 2;        // 64 MiB
  const size_t partBytes = (size_t)552 * 32768 * 4;         // 72.4 MB

  if (ws_size < ytBytes + partBytes) {
    k_fallback<<<dim3(NB * 16 * 16), dim3(256), 0, stream>>>(R, I, W, out);
    return;
  }

  unsigned short* Yt = (unsigned short*)d_ws;
  float* part = (float*)((char*)d_ws + ytBytes);

  k_prep<<<dim3(NB * 16 * 128), dim3(256), 0, stream>>>(R, I, W, Yt);
  k_gemm<<<dim3(512), dim3(256), 0, stream>>>(Yt, part);
  k_reduce<<<dim3(5120), dim3(256), 0, stream>>>(part, out);
  k_mirror<<<dim3(192), dim3(256), 0, stream>>>(out);
}

// Round 6
// 232.555 us; speedup vs baseline: 1.1436x; 1.0077x over previous
//
#include <hip/hip_runtime.h>
#include <cstdint>
#include <cstddef>

#define NB 4
#define NS 8192
#define ND 512
#define NP 1024
#define BK 32

typedef __bf16 bf16x8 __attribute__((ext_vector_type(8)));
typedef float f32x4 __attribute__((ext_vector_type(4)));

union FragU { uint4 u; bf16x8 h; };

__device__ __forceinline__ void gload16(const void* g, void* l) {
  __builtin_amdgcn_global_load_lds(
      (const __attribute__((address_space(1))) unsigned int*)g,
      (__attribute__((address_space(3))) unsigned int*)l, 16, 0, 0);
}

// ---------------------------------------------------------------------------
// Kernel A: Yt[b][p][s] = bf16( sqrt(w[b,s]) * (p<512 ? R[b,s,p] : I[b,s,p-512]) )
// u32-granular LDS transpose: phase 1 packs ADJACENT s-row pairs into one u32
// via v_cvt_pk_bf16_f32 (lo = even s, hi = odd s) and stores transposed into
// T[d][r]; phase 2 reads 4 contiguous u32 (8 s) per thread and writes
// coalesced 16B chunks. Replaces 32 scalar u16 LDS ops with 8 w + 4 r u32 ops.
// ---------------------------------------------------------------------------
__global__ __launch_bounds__(256)
void k_prep(const float* __restrict__ R, const float* __restrict__ I,
            const float* __restrict__ W, unsigned short* __restrict__ Yt) {
  __shared__ unsigned T[64][34];        // T[d][r] = {bf16(s=s0+2r) | bf16(s=s0+2r+1)<<16}
  const int t   = threadIdx.x;
  const int blk = blockIdx.x;
  const int sb  = blk & 127;            // 128 s-blocks of 64
  const int pb  = (blk >> 7) & 15;      // 16 p-blocks of 64
  const int b   = blk >> 11;            // 4 batches
  const float* src = (pb < 8) ? R : I;
  const int col0 = (pb & 7) * 64;
  const int s0 = sb * 64;
  const int c2 = t & 15;                // float4 chunk: d = c2*4 .. +3
  const int rp = t >> 4;                // 0..15
#pragma unroll
  for (int i = 0; i < 2; ++i) {
    const int r  = rp + 16 * i;         // 0..31 (s-pair index)
    const int sa = s0 + 2 * r;
    const float swa = sqrtf(W[b * NS + sa]);
    const float swb = sqrtf(W[b * NS + sa + 1]);
    const float4 va = *(const float4*)(src + (size_t)(b * NS + sa) * ND + col0 + c2 * 4);
    const float4 vb = *(const float4*)(src + (size_t)(b * NS + sa + 1) * ND + col0 + c2 * 4);
    unsigned p0, p1, p2, p3;
    asm("v_cvt_pk_bf16_f32 %0, %1, %2" : "=v"(p0) : "v"(va.x * swa), "v"(vb.x * swb));
    asm("v_cvt_pk_bf16_f32 %0, %1, %2" : "=v"(p1) : "v"(va.y * swa), "v"(vb.y * swb));
    asm("v_cvt_pk_bf16_f32 %0, %1, %2" : "=v"(p2) : "v"(va.z * swa), "v"(vb.z * swb));
    asm("v_cvt_pk_bf16_f32 %0, %1, %2" : "=v"(p3) : "v"(va.w * swa), "v"(vb.w * swb));
    T[c2 * 4 + 0][r] = p0;
    T[c2 * 4 + 1][r] = p1;
    T[c2 * 4 + 2][r] = p2;
    T[c2 * 4 + 3][r] = p3;
  }
  __syncthreads();
  const int sc = t & 7;                 // group of 4 u32 = 8 s
  const int d0 = t >> 3;                // 0..31
#pragma unroll
  for (int i = 0; i < 2; ++i) {
    const int d = d0 + 32 * i;
    uint4 o;
    o.x = T[d][sc * 4 + 0];
    o.y = T[d][sc * 4 + 1];
    o.z = T[d][sc * 4 + 2];
    o.w = T[d][sc * 4 + 3];
    *(uint4*)(Yt + (size_t)(b * NP + pb * 64 + d) * NS + s0 + sc * 8) = o;
  }
}

// ---------------------------------------------------------------------------
// Kernel B (round-4 verified): fused dual-output symmetric weighted-Gram GEMM.
// Flat-balanced: 512 blocks x exactly 20 K-steps over the 40*256 global step
// space. Pipeline: dbuf 2x32KiB, counted s_waitcnt vmcnt(8), raw s_barrier,
// T5 setprio. Swizzle (verified conflict-free): elem (m,k) of a panel at byte
// (m>>1)*128 + ((64*(m&1)+2k) ^ (((m>>1)&7)<<4)); linear gload_lds dest +
// inverse-swizzled global source.
// ---------------------------------------------------------------------------
__global__ __launch_bounds__(256, 2)
void k_gemm(const unsigned short* __restrict__ Yt, float* __restrict__ part) {
  __shared__ uint4 lds4[4096];          // 64 KiB = 2 bufs x (AR|AI|BR|BI)
  char* lds = (char*)lds4;
  static const int TMp[10] = {0,1,1,2,2,2,3,3,3,3};
  static const int TNp[10] = {0,0,1,0,1,2,0,1,2,3};
  const int j  = blockIdx.x;            // 0..511
  const int g0 = j * 20;
  const int g1 = g0 + 20;
  const int p0 = g0 >> 8;
  const int p1 = (g1 - 1) >> 8;
  const int t = threadIdx.x;
  const int l = t & 63, w = t >> 6;

  // staging lane geometry: linear LDS dest chunk -> inverse-swizzled source
  const int cj = l & 7, jj = l >> 3;
  const int ec = cj ^ jj;
  const int rbase = w * 16 + 2 * jj + (ec >> 2);
  const int colo  = (ec & 3) * 8;
  int dstoff[8];
#pragma unroll
  for (int u = 0; u < 8; ++u) dstoff[u] = (u >> 1) * 8192 + (u & 1) * 4096 + w * 1024;

  // fragment-read base
  const int gfr = l >> 4, e_ = l & 1, q = (l >> 1) & 7;
  const int ibase = ((l & 15) >> 1) * 128 + ((64 * e_ + 16 * gfr) ^ (q << 4));
  const int wm = w & 1, wn = w >> 1;
  const int mfb = wm * 4096, nfb = wn * 4096;
  const int lr = (l >> 4) * 4, lc = l & 15;

  for (int seg = 0; seg < 2; ++seg) {
    int pos, k0, ns;
    if (seg == 0) {
      pos = p0; k0 = g0 & 255;
      ns = 256 - k0; if (ns > 20) ns = 20;
    } else {
      if (p1 == p0) break;
      pos = p1; k0 = 0; ns = g1 & 255;  // in (0,20)
    }
    const int b = pos / 10, p = pos % 10;
    const int tm = TMp[p], tn = TNp[p];
    const int prow[4] = { tm * 128, 512 + tm * 128, tn * 128, 512 + tn * 128 };
    const unsigned short* gsrc[8];
#pragma unroll
    for (int u = 0; u < 8; ++u)
      gsrc[u] = Yt + (size_t)(b * NP + prow[u >> 1] + (u & 1) * 64 + rbase) * NS
                + (size_t)k0 * BK + colo;

    f32x4 accr[4][4], acci[4][4];
    const f32x4 zz = {0.f, 0.f, 0.f, 0.f};
#pragma unroll
    for (int a = 0; a < 4; ++a)
#pragma unroll
      for (int c = 0; c < 4; ++c) { accr[a][c] = zz; acci[a][c] = zz; }

    // prologue: stage step 0 into buf0, full drain
#pragma unroll
    for (int u = 0; u < 8; ++u) { gload16(gsrc[u], lds + dstoff[u]); gsrc[u] += BK; }
    __builtin_amdgcn_sched_barrier(0);
    asm volatile("s_waitcnt vmcnt(0)" ::: "memory");
    __builtin_amdgcn_s_barrier();

    int cur = 0;
    for (int ks = 0; ks < ns; ++ks) {
      const int cbase = cur * 32768;
      if (ks + 1 < ns) {
        const int nbase = cbase ^ 32768;
#pragma unroll
        for (int u = 0; u < 8; ++u) { gload16(gsrc[u], lds + nbase + dstoff[u]); gsrc[u] += BK; }
        __builtin_amdgcn_sched_barrier(0);
        asm volatile("s_waitcnt vmcnt(8)" ::: "memory");  // cur's 8 landed; nxt's 8 fly
      } else {
        asm volatile("s_waitcnt vmcnt(0)" ::: "memory");
      }
      __builtin_amdgcn_s_barrier();     // barrier1: all waves' cur staging visible

      FragU ar[4], ai[4];
#pragma unroll
      for (int mf = 0; mf < 4; ++mf) {
        ar[mf].u = *(const uint4*)(lds + cbase +        mfb + mf * 1024 + ibase);
        ai[mf].u = *(const uint4*)(lds + cbase + 8192 + mfb + mf * 1024 + ibase);
      }
      __builtin_amdgcn_s_setprio(1);
#pragma unroll
      for (int nf = 0; nf < 4; ++nf) {
        FragU br, bi, bin;
        br.u = *(const uint4*)(lds + cbase + 16384 + nfb + nf * 1024 + ibase);
        bi.u = *(const uint4*)(lds + cbase + 24576 + nfb + nf * 1024 + ibase);
        bin.u.x = bi.u.x ^ 0x80008000u;
        bin.u.y = bi.u.y ^ 0x80008000u;
        bin.u.z = bi.u.z ^ 0x80008000u;
        bin.u.w = bi.u.w ^ 0x80008000u;
#pragma unroll
        for (int mf = 0; mf < 4; ++mf) {
          accr[mf][nf] = __builtin_amdgcn_mfma_f32_16x16x32_bf16(ar[mf].h, br.h,  accr[mf][nf], 0, 0, 0);
          accr[mf][nf] = __builtin_amdgcn_mfma_f32_16x16x32_bf16(ai[mf].h, bi.h,  accr[mf][nf], 0, 0, 0);
          acci[mf][nf] = __builtin_amdgcn_mfma_f32_16x16x32_bf16(ai[mf].h, br.h,  acci[mf][nf], 0, 0, 0);
          acci[mf][nf] = __builtin_amdgcn_mfma_f32_16x16x32_bf16(ar[mf].h, bin.h, acci[mf][nf], 0, 0, 0);
        }
      }
      __builtin_amdgcn_s_setprio(0);
      __builtin_amdgcn_s_barrier();     // barrier2: reads done -> buf reusable
      cur ^= 1;
    }

    // segment epilogue: partial slot = (seg==0 ? j : 512+pos), [slot][o][128][128]
    const int slot = (seg == 0) ? j : (512 + pos);
    const size_t baser = (size_t)slot * 32768;
    const size_t basei = baser + 16384;
#pragma unroll
    for (int mf = 0; mf < 4; ++mf)
#pragma unroll
      for (int nf = 0; nf < 4; ++nf)
#pragma unroll
        for (int r = 0; r < 4; ++r) {
          const int mi = wm * 64 + mf * 16 + lr + r;
          const int ni = wn * 64 + nf * 16 + lc;
          part[baser + (size_t)mi * 128 + ni] = accr[mf][nf][r];
          part[basei + (size_t)mi * 128 + ni] = acci[mf][nf][r];
        }
  }
}

// ---------------------------------------------------------------------------
// Kernel C: sum contributing partial slots per position, write lower tiles.
// ---------------------------------------------------------------------------
__global__ __launch_bounds__(256)
void k_reduce(const float* __restrict__ part, float* __restrict__ out) {
  static const int TMp[10] = {0,1,1,2,2,2,3,3,3,3};
  static const int TNp[10] = {0,0,1,0,1,2,0,1,2,3};
  const int idx = blockIdx.x * 256 + threadIdx.x;   // < 1310720
  const int ni = idx & 127;
  const int mi = (idx >> 7) & 127;
  const int o  = (idx >> 14) & 1;
  const int P  = idx >> 15;                         // 0..39
  const int jlo = (256 * P + 19) / 20;
  const int jhi = (256 * P + 255) / 20;
  const size_t off = (size_t)o * 16384 + (size_t)mi * 128 + ni;
  float a = 0.f;
  for (int s = jlo; s <= jhi; ++s)
    a += part[(size_t)s * 32768 + off];
  if ((256 * P) % 20)
    a += part[(size_t)(512 + P) * 32768 + off];
  const int b = P / 10, p = P % 10;
  const int d = TMp[p] * 128 + mi;
  const int e = TNp[p] * 128 + ni;
  out[(size_t)o * 1048576 + (size_t)b * 262144 + (size_t)d * 512 + e] = a;
}

// ---------------------------------------------------------------------------
// Kernel D: mirror upper tiles (out_r symmetric, out_i antisymmetric).
// ---------------------------------------------------------------------------
__global__ __launch_bounds__(256)
void k_mirror(float* __restrict__ out) {
  __shared__ float T[64][65];
  static const int UM[6] = {0,0,0,1,1,2};
  static const int UN[6] = {1,2,3,2,3,3};
  const int m = blockIdx.x;               // 192
  const int sub = m & 3;
  const int b   = (m >> 2) & 3;
  const int o   = (m >> 4) & 1;
  const int u   = m >> 5;
  const int d0 = UM[u] * 128 + (sub & 1) * 64;
  const int e0 = UN[u] * 128 + ((sub >> 1) & 1) * 64;
  const float sign = o ? -1.f : 1.f;
  float* base = out + (size_t)o * 1048576 + (size_t)b * 262144;
  const int t  = threadIdx.x;
  const int c4 = (t & 15) * 4;
  const int r0 = t >> 4;
#pragma unroll
  for (int i = 0; i < 4; ++i) {
    const int r = r0 + i * 16;
    const float4 v = *(const float4*)(base + (size_t)(e0 + r) * 512 + d0 + c4);
    T[c4 + 0][r] = v.x; T[c4 + 1][r] = v.y;
    T[c4 + 2][r] = v.z; T[c4 + 3][r] = v.w;
  }
  __syncthreads();
#pragma unroll
  for (int i = 0; i < 4; ++i) {
    const int r = r0 + i * 16;
    float4 wv;
    wv.x = sign * T[r][c4 + 0]; wv.y = sign * T[r][c4 + 1];
    wv.z = sign * T[r][c4 + 2]; wv.w = sign * T[r][c4 + 3];
    *(float4*)(base + (size_t)(d0 + r) * 512 + e0 + c4) = wv;
  }
}

// ---------------------------------------------------------------------------
// Zero-workspace f32 fallback (ws too small). Safe, slow.
// ---------------------------------------------------------------------------
__global__ __launch_bounds__(256)
void k_fallback(const float* __restrict__ R, const float* __restrict__ I,
                const float* __restrict__ W, float* __restrict__ out) {
  __shared__ float Rd[64][32], Id[64][32], Re[64][32], Ie[64][32];
  const int blk = blockIdx.x;
  const int et = blk & 15, dt = (blk >> 4) & 15, b = blk >> 8;
  const int d0 = dt * 32, e0 = et * 32;
  const int t = threadIdx.x;
  const int dd = t >> 3;
  const int ee0 = (t & 7) * 4;
  float ar[4] = {0,0,0,0}, ai[4] = {0,0,0,0};
  for (int s0 = 0; s0 < NS; s0 += 64) {
#pragma unroll
    for (int k = 0; k < 8; ++k) {
      const int idx = t + k * 256;
      const int row = idx >> 5, col = idx & 31;
      const float sw = sqrtf(W[b * NS + s0 + row]);
      const size_t gr = (size_t)(b * NS + s0 + row) * ND;
      Rd[row][col] = R[gr + d0 + col] * sw;
      Id[row][col] = I[gr + d0 + col] * sw;
      Re[row][col] = R[gr + e0 + col] * sw;
      Ie[row][col] = I[gr + e0 + col] * sw;
    }
    __syncthreads();
    for (int s = 0; s < 64; ++s) {
      const float rd = Rd[s][dd], id = Id[s][dd];
#pragma unroll
      for (int jx = 0; jx < 4; ++jx) {
        const float re = Re[s][ee0 + jx], ie = Ie[s][ee0 + jx];
        ar[jx] += rd * re + id * ie;
        ai[jx] += id * re - rd * ie;
      }
    }
    __syncthreads();
  }
  const size_t ob = (size_t)b * 262144;
#pragma unroll
  for (int jx = 0; jx < 4; ++jx) {
    out[          ob + (size_t)(d0 + dd) * 512 + e0 + ee0 + jx] = ar[jx];
    out[1048576 + ob + (size_t)(d0 + dd) * 512 + e0 + ee0 + jx] = ai[jx];
  }
}

extern "C" void kernel_launch(void* const* d_in, const int* in_sizes, int n_in,
                              void* d_out, int out_size, void* d_ws, size_t ws_size,
                              hipStream_t stream) {
  const float* R = (const float*)d_in[0];
  const float* I = (const float*)d_in[1];
  const float* W = (const float*)d_in[2];
  float* out = (float*)d_out;
  const size_t ytBytes   = (size_t)NB * NP * NS * 2;        // 64 MiB
  const size_t partBytes = (size_t)552 * 32768 * 4;         // 72.4 MB

  if (ws_size < ytBytes + partBytes) {
    k_fallback<<<dim3(NB * 16 * 16), dim3(256), 0, stream>>>(R, I, W, out);
    return;
  }

  unsigned short* Yt = (unsigned short*)d_ws;
  float* part = (float*)((char*)d_ws + ytBytes);

  k_prep<<<dim3(NB * 16 * 128), dim3(256), 0, stream>>>(R, I, W, Yt);
  k_gemm<<<dim3(512), dim3(256), 0, stream>>>(Yt, part);
  k_reduce<<<dim3(5120), dim3(256), 0, stream>>>(part, out);
  k_mirror<<<dim3(192), dim3(256), 0, stream>>>(out);
}

// Round 8
// 228.956 us; speedup vs baseline: 1.1616x; 1.0157x over previous
//
#include <hip/hip_runtime.h>
#include <cstdint>
#include <cstddef>

#define NB 4
#define NS 8192
#define ND 512
#define NP 1024
#define BK 32

typedef __bf16 bf16x8 __attribute__((ext_vector_type(8)));
typedef float f32x4 __attribute__((ext_vector_type(4)));

union FragU { uint4 u; bf16x8 h; };

__device__ __forceinline__ void gload16(const void* g, void* l) {
  __builtin_amdgcn_global_load_lds(
      (const __attribute__((address_space(1))) unsigned int*)g,
      (__attribute__((address_space(3))) unsigned int*)l, 16, 0, 0);
}

// ---------------------------------------------------------------------------
// Kernel A: Yt[b][p][s] = bf16( sqrt(w[b,s]) * (p<512 ? R[b,s,p] : I[b,s,p-512]) )
// u32-granular LDS transpose (validated round 6): v_cvt_pk_bf16_f32 packs
// adjacent s-row pairs; phase 2 writes coalesced 16B chunks.
// ---------------------------------------------------------------------------
__global__ __launch_bounds__(256)
void k_prep(const float* __restrict__ R, const float* __restrict__ I,
            const float* __restrict__ W, unsigned short* __restrict__ Yt) {
  __shared__ unsigned T[64][34];
  const int t   = threadIdx.x;
  const int blk = blockIdx.x;
  const int sb  = blk & 127;
  const int pb  = (blk >> 7) & 15;
  const int b   = blk >> 11;
  const float* src = (pb < 8) ? R : I;
  const int col0 = (pb & 7) * 64;
  const int s0 = sb * 64;
  const int c2 = t & 15;
  const int rp = t >> 4;
#pragma unroll
  for (int i = 0; i < 2; ++i) {
    const int r  = rp + 16 * i;
    const int sa = s0 + 2 * r;
    const float swa = sqrtf(W[b * NS + sa]);
    const float swb = sqrtf(W[b * NS + sa + 1]);
    const float4 va = *(const float4*)(src + (size_t)(b * NS + sa) * ND + col0 + c2 * 4);
    const float4 vb = *(const float4*)(src + (size_t)(b * NS + sa + 1) * ND + col0 + c2 * 4);
    unsigned p0, p1, p2, p3;
    asm("v_cvt_pk_bf16_f32 %0, %1, %2" : "=v"(p0) : "v"(va.x * swa), "v"(vb.x * swb));
    asm("v_cvt_pk_bf16_f32 %0, %1, %2" : "=v"(p1) : "v"(va.y * swa), "v"(vb.y * swb));
    asm("v_cvt_pk_bf16_f32 %0, %1, %2" : "=v"(p2) : "v"(va.z * swa), "v"(vb.z * swb));
    asm("v_cvt_pk_bf16_f32 %0, %1, %2" : "=v"(p3) : "v"(va.w * swa), "v"(vb.w * swb));
    T[c2 * 4 + 0][r] = p0;
    T[c2 * 4 + 1][r] = p1;
    T[c2 * 4 + 2][r] = p2;
    T[c2 * 4 + 3][r] = p3;
  }
  __syncthreads();
  const int sc = t & 7;
  const int d0 = t >> 3;
#pragma unroll
  for (int i = 0; i < 2; ++i) {
    const int d = d0 + 32 * i;
    uint4 o;
    o.x = T[d][sc * 4 + 0];
    o.y = T[d][sc * 4 + 1];
    o.z = T[d][sc * 4 + 2];
    o.w = T[d][sc * 4 + 3];
    *(uint4*)(Yt + (size_t)(b * NP + pb * 64 + d) * NS + s0 + sc * 8) = o;
  }
}

// ---------------------------------------------------------------------------
// Kernel B: fused dual-output symmetric weighted-Gram GEMM.
// Round-7 retile: SAME proven 2-barrier counted-vmcnt dbuf schedule + swizzle,
// but 512 threads (8 waves, wave grid 4m x 2n, per-wave 2x4 frags) so VGPR
// stays <=128 -> 4 waves/SIMD (2 blocks x 8 waves / CU) for latency hiding.
// T1 XCD swizzle: consecutive logical j (same tile) land on one XCD's L2.
// Flat-balanced: 512 blocks x exactly 20 K-steps over the 40*256 step space.
// Swizzle layout per 8KiB panel (verified conflict-free rounds 2-6):
// elem (m,k) at byte (m>>1)*128 + ((64*(m&1)+2k) ^ (((m>>1)&7)<<4)).
// ---------------------------------------------------------------------------
__global__ __launch_bounds__(512, 4)
void k_gemm(const unsigned short* __restrict__ Yt, float* __restrict__ part) {
  __shared__ uint4 lds4[4096];          // 64 KiB = 2 bufs x (AR|AI|BR|BI)
  char* lds = (char*)lds4;
  static const int TMp[10] = {0,1,1,2,2,2,3,3,3,3};
  static const int TNp[10] = {0,0,1,0,1,2,0,1,2,3};
  const int bid = blockIdx.x;
  const int j   = (bid & 7) * 64 + (bid >> 3);   // XCD-aware bijective swizzle
  const int g0 = j * 20;
  const int g1 = g0 + 20;
  const int p0 = g0 >> 8;
  const int p1 = (g1 - 1) >> 8;
  const int t = threadIdx.x;
  const int l = t & 63, w = t >> 6;              // w = 0..7

  // staging lane geometry: linear LDS dest chunk -> inverse-swizzled source.
  // Per step each wave issues 4 gload16 (panel u=0..3, KB w = rows w*16..+15).
  const int cj = l & 7, jj = l >> 3;
  const int ec = cj ^ jj;
  const int rbase = w * 16 + 2 * jj + (ec >> 2);
  const int colo  = (ec & 3) * 8;
  int dstoff[4];
#pragma unroll
  for (int u = 0; u < 4; ++u) dstoff[u] = u * 8192 + w * 1024;

  // fragment-read base (unchanged formula)
  const int gfr = l >> 4, e_ = l & 1, q = (l >> 1) & 7;
  const int ibase = ((l & 15) >> 1) * 128 + ((64 * e_ + 16 * gfr) ^ (q << 4));
  const int wm = w & 3, wn = w >> 2;             // 4 m-positions x 2 n-positions
  const int mfb = wm * 2048;                     // rows [wm*32 .. +32)
  const int nfb = wn * 4096;                     // cols [wn*64 .. +64)
  const int lr = (l >> 4) * 4, lc = l & 15;

  for (int seg = 0; seg < 2; ++seg) {
    int pos, k0, ns;
    if (seg == 0) {
      pos = p0; k0 = g0 & 255;
      ns = 256 - k0; if (ns > 20) ns = 20;
    } else {
      if (p1 == p0) break;
      pos = p1; k0 = 0; ns = g1 & 255;  // in (0,20)
    }
    const int b = pos / 10, p = pos % 10;
    const int tm = TMp[p], tn = TNp[p];
    const int prow[4] = { tm * 128, 512 + tm * 128, tn * 128, 512 + tn * 128 };
    const unsigned short* gsrc[4];
#pragma unroll
    for (int u = 0; u < 4; ++u)
      gsrc[u] = Yt + (size_t)(b * NP + prow[u] + rbase) * NS
                + (size_t)k0 * BK + colo;

    f32x4 accr[2][4], acci[2][4];
    const f32x4 zz = {0.f, 0.f, 0.f, 0.f};
#pragma unroll
    for (int a = 0; a < 2; ++a)
#pragma unroll
      for (int c = 0; c < 4; ++c) { accr[a][c] = zz; acci[a][c] = zz; }

    // prologue: stage step 0 into buf0, full drain
#pragma unroll
    for (int u = 0; u < 4; ++u) { gload16(gsrc[u], lds + dstoff[u]); gsrc[u] += BK; }
    __builtin_amdgcn_sched_barrier(0);
    asm volatile("s_waitcnt vmcnt(0)" ::: "memory");
    __builtin_amdgcn_s_barrier();

    int cur = 0;
    for (int ks = 0; ks < ns; ++ks) {
      const int cbase = cur * 32768;
      if (ks + 1 < ns) {
        const int nbase = cbase ^ 32768;
#pragma unroll
        for (int u = 0; u < 4; ++u) { gload16(gsrc[u], lds + nbase + dstoff[u]); gsrc[u] += BK; }
        __builtin_amdgcn_sched_barrier(0);
        asm volatile("s_waitcnt vmcnt(4)" ::: "memory");  // cur's 4 landed; nxt's 4 fly
      } else {
        asm volatile("s_waitcnt vmcnt(0)" ::: "memory");
      }
      __builtin_amdgcn_s_barrier();     // barrier1: all waves' cur staging visible

      FragU ar[2], ai[2];
#pragma unroll
      for (int mf = 0; mf < 2; ++mf) {
        ar[mf].u = *(const uint4*)(lds + cbase +        mfb + mf * 1024 + ibase);
        ai[mf].u = *(const uint4*)(lds + cbase + 8192 + mfb + mf * 1024 + ibase);
      }
      __builtin_amdgcn_s_setprio(1);
#pragma unroll
      for (int nf = 0; nf < 4; ++nf) {
        FragU br, bi, bin;
        br.u = *(const uint4*)(lds + cbase + 16384 + nfb + nf * 1024 + ibase);
        bi.u = *(const uint4*)(lds + cbase + 24576 + nfb + nf * 1024 + ibase);
        bin.u.x = bi.u.x ^ 0x80008000u;
        bin.u.y = bi.u.y ^ 0x80008000u;
        bin.u.z = bi.u.z ^ 0x80008000u;
        bin.u.w = bi.u.w ^ 0x80008000u;
#pragma unroll
        for (int mf = 0; mf < 2; ++mf) {
          accr[mf][nf] = __builtin_amdgcn_mfma_f32_16x16x32_bf16(ar[mf].h, br.h,  accr[mf][nf], 0, 0, 0);
          accr[mf][nf] = __builtin_amdgcn_mfma_f32_16x16x32_bf16(ai[mf].h, bi.h,  accr[mf][nf], 0, 0, 0);
          acci[mf][nf] = __builtin_amdgcn_mfma_f32_16x16x32_bf16(ai[mf].h, br.h,  acci[mf][nf], 0, 0, 0);
          acci[mf][nf] = __builtin_amdgcn_mfma_f32_16x16x32_bf16(ar[mf].h, bin.h, acci[mf][nf], 0, 0, 0);
        }
      }
      __builtin_amdgcn_s_setprio(0);
      __builtin_amdgcn_s_barrier();     // barrier2: reads done -> buf reusable
      cur ^= 1;
    }

    // segment epilogue: partial slot = (seg==0 ? j : 512+pos), [slot][o][128][128]
    const int slot = (seg == 0) ? j : (512 + pos);
    const size_t baser = (size_t)slot * 32768;
    const size_t basei = baser + 16384;
#pragma unroll
    for (int mf = 0; mf < 2; ++mf)
#pragma unroll
      for (int nf = 0; nf < 4; ++nf)
#pragma unroll
        for (int r = 0; r < 4; ++r) {
          const int mi = wm * 32 + mf * 16 + lr + r;
          const int ni = wn * 64 + nf * 16 + lc;
          part[baser + (size_t)mi * 128 + ni] = accr[mf][nf][r];
          part[basei + (size_t)mi * 128 + ni] = acci[mf][nf][r];
        }
  }
}

// ---------------------------------------------------------------------------
// Kernel C: sum contributing partial slots per position (float4-vectorized),
// write lower tiles.
// ---------------------------------------------------------------------------
__global__ __launch_bounds__(256)
void k_reduce(const float* __restrict__ part, float* __restrict__ out) {
  static const int TMp[10] = {0,1,1,2,2,2,3,3,3,3};
  static const int TNp[10] = {0,0,1,0,1,2,0,1,2,3};
  const int idx = blockIdx.x * 256 + threadIdx.x;   // < 327680
  const int n4 = idx & 31;                          // float4 col group
  const int mi = (idx >> 5) & 127;
  const int o  = (idx >> 12) & 1;
  const int P  = idx >> 13;                         // 0..39
  const int jlo = (256 * P + 19) / 20;
  const int jhi = (256 * P + 255) / 20;
  const size_t off = (size_t)o * 16384 + (size_t)mi * 128 + n4 * 4;
  float4 a = {0.f, 0.f, 0.f, 0.f};
  for (int s = jlo; s <= jhi; ++s) {
    const float4 v = *(const float4*)(part + (size_t)s * 32768 + off);
    a.x += v.x; a.y += v.y; a.z += v.z; a.w += v.w;
  }
  if ((256 * P) % 20) {
    const float4 v = *(const float4*)(part + (size_t)(512 + P) * 32768 + off);
    a.x += v.x; a.y += v.y; a.z += v.z; a.w += v.w;
  }
  const int b = P / 10, p = P % 10;
  const int d = TMp[p] * 128 + mi;
  const int e = TNp[p] * 128 + n4 * 4;
  *(float4*)(out + (size_t)o * 1048576 + (size_t)b * 262144
             + (size_t)d * 512 + e) = a;
}

// ---------------------------------------------------------------------------
// Kernel D: mirror upper tiles (out_r symmetric, out_i antisymmetric).
// ---------------------------------------------------------------------------
__global__ __launch_bounds__(256)
void k_mirror(float* __restrict__ out) {
  __shared__ float T[64][65];
  static const int UM[6] = {0,0,0,1,1,2};
  static const int UN[6] = {1,2,3,2,3,3};
  const int m = blockIdx.x;               // 192
  const int sub = m & 3;
  const int b   = (m >> 2) & 3;
  const int o   = (m >> 4) & 1;
  const int u   = m >> 5;
  const int d0 = UM[u] * 128 + (sub & 1) * 64;
  const int e0 = UN[u] * 128 + ((sub >> 1) & 1) * 64;
  const float sign = o ? -1.f : 1.f;
  float* base = out + (size_t)o * 1048576 + (size_t)b * 262144;
  const int t  = threadIdx.x;
  const int c4 = (t & 15) * 4;
  const int r0 = t >> 4;
#pragma unroll
  for (int i = 0; i < 4; ++i) {
    const int r = r0 + i * 16;
    const float4 v = *(const float4*)(base + (size_t)(e0 + r) * 512 + d0 + c4);
    T[c4 + 0][r] = v.x; T[c4 + 1][r] = v.y;
    T[c4 + 2][r] = v.z; T[c4 + 3][r] = v.w;
  }
  __syncthreads();
#pragma unroll
  for (int i = 0; i < 4; ++i) {
    const int r = r0 + i * 16;
    float4 wv;
    wv.x = sign * T[r][c4 + 0]; wv.y = sign * T[r][c4 + 1];
    wv.z = sign * T[r][c4 + 2]; wv.w = sign * T[r][c4 + 3];
    *(float4*)(base + (size_t)(d0 + r) * 512 + e0 + c4) = wv;
  }
}

// ---------------------------------------------------------------------------
// Zero-workspace f32 fallback (ws too small). Safe, slow.
// ---------------------------------------------------------------------------
__global__ __launch_bounds__(256)
void k_fallback(const float* __restrict__ R, const float* __restrict__ I,
                const float* __restrict__ W, float* __restrict__ out) {
  __shared__ float Rd[64][32], Id[64][32], Re[64][32], Ie[64][32];
  const int blk = blockIdx.x;
  const int et = blk & 15, dt = (blk >> 4) & 15, b = blk >> 8;
  const int d0 = dt * 32, e0 = et * 32;
  const int t = threadIdx.x;
  const int dd = t >> 3;
  const int ee0 = (t & 7) * 4;
  float ar[4] = {0,0,0,0}, ai[4] = {0,0,0,0};
  for (int s0 = 0; s0 < NS; s0 += 64) {
#pragma unroll
    for (int k = 0; k < 8; ++k) {
      const int idx = t + k * 256;
      const int row = idx >> 5, col = idx & 31;
      const float sw = sqrtf(W[b * NS + s0 + row]);
      const size_t gr = (size_t)(b * NS + s0 + row) * ND;
      Rd[row][col] = R[gr + d0 + col] * sw;
      Id[row][col] = I[gr + d0 + col] * sw;
      Re[row][col] = R[gr + e0 + col] * sw;
      Ie[row][col] = I[gr + e0 + col] * sw;
    }
    __syncthreads();
    for (int s = 0; s < 64; ++s) {
      const float rd = Rd[s][dd], id = Id[s][dd];
#pragma unroll
      for (int jx = 0; jx < 4; ++jx) {
        const float re = Re[s][ee0 + jx], ie = Ie[s][ee0 + jx];
        ar[jx] += rd * re + id * ie;
        ai[jx] += id * re - rd * ie;
      }
    }
    __syncthreads();
  }
  const size_t ob = (size_t)b * 262144;
#pragma unroll
  for (int jx = 0; jx < 4; ++jx) {
    out[          ob + (size_t)(d0 + dd) * 512 + e0 + ee0 + jx] = ar[jx];
    out[1048576 + ob + (size_t)(d0 + dd) * 512 + e0 + ee0 + jx] = ai[jx];
  }
}

extern "C" void kernel_launch(void* const* d_in, const int* in_sizes, int n_in,
                              void* d_out, int out_size, void* d_ws, size_t ws_size,
                              hipStream_t stream) {
  const float* R = (const float*)d_in[0];
  const float* I = (const float*)d_in[1];
  const float* W = (const float*)d_in[2];
  float* out = (float*)d_out;
  const size_t ytBytes   = (size_t)NB * NP * NS * 2;        // 64 MiB
  const size_t partBytes = (size_t)552 * 32768 * 4;         // 72.4 MB

  if (ws_size < ytBytes + partBytes) {
    k_fallback<<<dim3(NB * 16 * 16), dim3(256), 0, stream>>>(R, I, W, out);
    return;
  }

  unsigned short* Yt = (unsigned short*)d_ws;
  float* part = (float*)((char*)d_ws + ytBytes);

  k_prep<<<dim3(NB * 16 * 128), dim3(256), 0, stream>>>(R, I, W, Yt);
  k_gemm<<<dim3(512), dim3(512), 0, stream>>>(Yt, part);
  k_reduce<<<dim3(1280), dim3(256), 0, stream>>>(part, out);
  k_mirror<<<dim3(192), dim3(256), 0, stream>>>(out);
}

// Round 9
// 228.292 us; speedup vs baseline: 1.1650x; 1.0029x over previous
//
#include <hip/hip_runtime.h>
#include <cstdint>
#include <cstddef>

#define NB 4
#define NS 8192
#define ND 512
#define NP 1024
#define BK 32

typedef __bf16 bf16x8 __attribute__((ext_vector_type(8)));
typedef float f32x4 __attribute__((ext_vector_type(4)));

union FragU { uint4 u; bf16x8 h; };

__device__ __forceinline__ void gload16(const void* g, void* l) {
  __builtin_amdgcn_global_load_lds(
      (const __attribute__((address_space(1))) unsigned int*)g,
      (__attribute__((address_space(3))) unsigned int*)l, 16, 0, 0);
}

// ---------------------------------------------------------------------------
// Kernel A v3: Yt[b][p][s] = bf16( sqrt(w[b,s]) * (p<512 ? R : I)[b,s,p%512] )
// 64d x 128s tile. Phase 1: 8-deep float4 MLP, v_cvt_pk_bf16_f32 packs s-pairs
// (lo=even s, hi=odd s — validated round 6), XOR-swizzled LDS cols (<=2-way).
// Phase 2: b128 LDS reads, 256-B contiguous store runs (16 lanes/row).
// ---------------------------------------------------------------------------
__global__ __launch_bounds__(256)
void k_prep(const float* __restrict__ R, const float* __restrict__ I,
            const float* __restrict__ W, unsigned short* __restrict__ Yt) {
  __shared__ unsigned T[64][68];        // [d][s-pair], col stored ^ (4*(d>>4))
  const int t   = threadIdx.x;
  const int blk = blockIdx.x;
  const int sb  = blk & 63;             // 64 s-tiles of 128
  const int pb  = (blk >> 6) & 15;      // 16 p-tiles of 64
  const int b   = blk >> 10;            // 4 batches
  const float* src = (pb < 8) ? R : I;
  const int col0 = (pb & 7) * 64;
  const int s0 = sb * 128;
  const int c2 = t & 15;                // d-chunk: d = c2*4 .. +3
  const int rp = t >> 4;                // 0..15 s-pair base
  const int key1 = 4 * (c2 >> 2);       // write-side XOR key (bits 2-3)
#pragma unroll
  for (int i = 0; i < 4; ++i) {
    const int pp = rp + 16 * i;         // s-pair 0..63
    const int sa = s0 + 2 * pp;
    const float2 w2 = *(const float2*)(W + b * NS + sa);
    const float swa = sqrtf(w2.x);
    const float swb = sqrtf(w2.y);
    const float4 va = *(const float4*)(src + (size_t)(b * NS + sa) * ND + col0 + c2 * 4);
    const float4 vb = *(const float4*)(src + (size_t)(b * NS + sa + 1) * ND + col0 + c2 * 4);
    unsigned p0, p1, p2, p3;
    asm("v_cvt_pk_bf16_f32 %0, %1, %2" : "=v"(p0) : "v"(va.x * swa), "v"(vb.x * swb));
    asm("v_cvt_pk_bf16_f32 %0, %1, %2" : "=v"(p1) : "v"(va.y * swa), "v"(vb.y * swb));
    asm("v_cvt_pk_bf16_f32 %0, %1, %2" : "=v"(p2) : "v"(va.z * swa), "v"(vb.z * swb));
    asm("v_cvt_pk_bf16_f32 %0, %1, %2" : "=v"(p3) : "v"(va.w * swa), "v"(vb.w * swb));
    const int col = pp ^ key1;
    T[c2 * 4 + 0][col] = p0;
    T[c2 * 4 + 1][col] = p1;
    T[c2 * 4 + 2][col] = p2;
    T[c2 * 4 + 3][col] = p3;
  }
  __syncthreads();
  const int c  = t & 15;                // output 16B chunk (8 s)
  const int dr = t >> 4;                // 0..15
#pragma unroll
  for (int i = 0; i < 4; ++i) {
    const int d = dr + 16 * i;
    const int phys = (c * 4) ^ (4 * ((d >> 4) & 3));   // logical col c*4 (+k)
    uint4 o;
    o.x = T[d][phys + 0];
    o.y = T[d][phys + 1];
    o.z = T[d][phys + 2];
    o.w = T[d][phys + 3];
    *(uint4*)(Yt + (size_t)(b * NP + pb * 64 + d) * NS + s0 + c * 8) = o;
  }
}

// ---------------------------------------------------------------------------
// Kernel B (validated round 8): fused dual-output symmetric weighted-Gram GEMM.
// 512 threads (8 waves, 4m x 2n), 2-barrier counted-vmcnt dbuf, T5 setprio,
// T1 XCD swizzle, flat-balanced 512 blocks x 20 K-steps.
// Panel swizzle: elem (m,k) at byte (m>>1)*128 + ((64*(m&1)+2k) ^ (((m>>1)&7)<<4)).
// ---------------------------------------------------------------------------
__global__ __launch_bounds__(512, 4)
void k_gemm(const unsigned short* __restrict__ Yt, float* __restrict__ part) {
  __shared__ uint4 lds4[4096];          // 64 KiB = 2 bufs x (AR|AI|BR|BI)
  char* lds = (char*)lds4;
  static const int TMp[10] = {0,1,1,2,2,2,3,3,3,3};
  static const int TNp[10] = {0,0,1,0,1,2,0,1,2,3};
  const int bid = blockIdx.x;
  const int j   = (bid & 7) * 64 + (bid >> 3);   // XCD-aware bijective swizzle
  const int g0 = j * 20;
  const int g1 = g0 + 20;
  const int p0 = g0 >> 8;
  const int p1 = (g1 - 1) >> 8;
  const int t = threadIdx.x;
  const int l = t & 63, w = t >> 6;              // w = 0..7

  const int cj = l & 7, jj = l >> 3;
  const int ec = cj ^ jj;
  const int rbase = w * 16 + 2 * jj + (ec >> 2);
  const int colo  = (ec & 3) * 8;
  int dstoff[4];
#pragma unroll
  for (int u = 0; u < 4; ++u) dstoff[u] = u * 8192 + w * 1024;

  const int gfr = l >> 4, e_ = l & 1, q = (l >> 1) & 7;
  const int ibase = ((l & 15) >> 1) * 128 + ((64 * e_ + 16 * gfr) ^ (q << 4));
  const int wm = w & 3, wn = w >> 2;
  const int mfb = wm * 2048;
  const int nfb = wn * 4096;
  const int lr = (l >> 4) * 4, lc = l & 15;

  for (int seg = 0; seg < 2; ++seg) {
    int pos, k0, ns;
    if (seg == 0) {
      pos = p0; k0 = g0 & 255;
      ns = 256 - k0; if (ns > 20) ns = 20;
    } else {
      if (p1 == p0) break;
      pos = p1; k0 = 0; ns = g1 & 255;  // in (0,20)
    }
    const int b = pos / 10, p = pos % 10;
    const int tm = TMp[p], tn = TNp[p];
    const int prow[4] = { tm * 128, 512 + tm * 128, tn * 128, 512 + tn * 128 };
    const unsigned short* gsrc[4];
#pragma unroll
    for (int u = 0; u < 4; ++u)
      gsrc[u] = Yt + (size_t)(b * NP + prow[u] + rbase) * NS
                + (size_t)k0 * BK + colo;

    f32x4 accr[2][4], acci[2][4];
    const f32x4 zz = {0.f, 0.f, 0.f, 0.f};
#pragma unroll
    for (int a = 0; a < 2; ++a)
#pragma unroll
      for (int c = 0; c < 4; ++c) { accr[a][c] = zz; acci[a][c] = zz; }

#pragma unroll
    for (int u = 0; u < 4; ++u) { gload16(gsrc[u], lds + dstoff[u]); gsrc[u] += BK; }
    __builtin_amdgcn_sched_barrier(0);
    asm volatile("s_waitcnt vmcnt(0)" ::: "memory");
    __builtin_amdgcn_s_barrier();

    int cur = 0;
    for (int ks = 0; ks < ns; ++ks) {
      const int cbase = cur * 32768;
      if (ks + 1 < ns) {
        const int nbase = cbase ^ 32768;
#pragma unroll
        for (int u = 0; u < 4; ++u) { gload16(gsrc[u], lds + nbase + dstoff[u]); gsrc[u] += BK; }
        __builtin_amdgcn_sched_barrier(0);
        asm volatile("s_waitcnt vmcnt(4)" ::: "memory");
      } else {
        asm volatile("s_waitcnt vmcnt(0)" ::: "memory");
      }
      __builtin_amdgcn_s_barrier();

      FragU ar[2], ai[2];
#pragma unroll
      for (int mf = 0; mf < 2; ++mf) {
        ar[mf].u = *(const uint4*)(lds + cbase +        mfb + mf * 1024 + ibase);
        ai[mf].u = *(const uint4*)(lds + cbase + 8192 + mfb + mf * 1024 + ibase);
      }
      __builtin_amdgcn_s_setprio(1);
#pragma unroll
      for (int nf = 0; nf < 4; ++nf) {
        FragU br, bi, bin;
        br.u = *(const uint4*)(lds + cbase + 16384 + nfb + nf * 1024 + ibase);
        bi.u = *(const uint4*)(lds + cbase + 24576 + nfb + nf * 1024 + ibase);
        bin.u.x = bi.u.x ^ 0x80008000u;
        bin.u.y = bi.u.y ^ 0x80008000u;
        bin.u.z = bi.u.z ^ 0x80008000u;
        bin.u.w = bi.u.w ^ 0x80008000u;
#pragma unroll
        for (int mf = 0; mf < 2; ++mf) {
          accr[mf][nf] = __builtin_amdgcn_mfma_f32_16x16x32_bf16(ar[mf].h, br.h,  accr[mf][nf], 0, 0, 0);
          accr[mf][nf] = __builtin_amdgcn_mfma_f32_16x16x32_bf16(ai[mf].h, bi.h,  accr[mf][nf], 0, 0, 0);
          acci[mf][nf] = __builtin_amdgcn_mfma_f32_16x16x32_bf16(ai[mf].h, br.h,  acci[mf][nf], 0, 0, 0);
          acci[mf][nf] = __builtin_amdgcn_mfma_f32_16x16x32_bf16(ar[mf].h, bin.h, acci[mf][nf], 0, 0, 0);
        }
      }
      __builtin_amdgcn_s_setprio(0);
      __builtin_amdgcn_s_barrier();
      cur ^= 1;
    }

    const int slot = (seg == 0) ? j : (512 + pos);
    const size_t baser = (size_t)slot * 32768;
    const size_t basei = baser + 16384;
#pragma unroll
    for (int mf = 0; mf < 2; ++mf)
#pragma unroll
      for (int nf = 0; nf < 4; ++nf)
#pragma unroll
        for (int r = 0; r < 4; ++r) {
          const int mi = wm * 32 + mf * 16 + lr + r;
          const int ni = wn * 64 + nf * 16 + lc;
          part[baser + (size_t)mi * 128 + ni] = accr[mf][nf][r];
          part[basei + (size_t)mi * 128 + ni] = acci[mf][nf][r];
        }
  }
}

// ---------------------------------------------------------------------------
// Kernel C (fused reduce+mirror): sum contributing partial slots, write the
// lower tile element (d,e) coalesced; for off-diagonal tiles also write the
// mirrored (e,d) element (out_r symmetric, out_i antisymmetric). Each output
// element written exactly once.
// ---------------------------------------------------------------------------
__global__ __launch_bounds__(256)
void k_reduce(const float* __restrict__ part, float* __restrict__ out) {
  static const int TMp[10] = {0,1,1,2,2,2,3,3,3,3};
  static const int TNp[10] = {0,0,1,0,1,2,0,1,2,3};
  const int idx = blockIdx.x * 256 + threadIdx.x;   // < 327680
  const int n4 = idx & 31;
  const int mi = (idx >> 5) & 127;
  const int o  = (idx >> 12) & 1;
  const int P  = idx >> 13;                         // 0..39
  const int jlo = (256 * P + 19) / 20;
  const int jhi = (256 * P + 255) / 20;
  const size_t off = (size_t)o * 16384 + (size_t)mi * 128 + n4 * 4;
  float4 a = {0.f, 0.f, 0.f, 0.f};
  for (int s = jlo; s <= jhi; ++s) {
    const float4 v = *(const float4*)(part + (size_t)s * 32768 + off);
    a.x += v.x; a.y += v.y; a.z += v.z; a.w += v.w;
  }
  if ((256 * P) % 20) {
    const float4 v = *(const float4*)(part + (size_t)(512 + P) * 32768 + off);
    a.x += v.x; a.y += v.y; a.z += v.z; a.w += v.w;
  }
  const int b = P / 10, p = P % 10;
  const int tm = TMp[p], tn = TNp[p];
  const int d = tm * 128 + mi;
  const int e = tn * 128 + n4 * 4;
  float* base = out + (size_t)o * 1048576 + (size_t)b * 262144;
  *(float4*)(base + (size_t)d * 512 + e) = a;
  if (tm != tn) {                       // mirror to upper tile
    const float sg = o ? -1.f : 1.f;
    base[(size_t)(e + 0) * 512 + d] = sg * a.x;
    base[(size_t)(e + 1) * 512 + d] = sg * a.y;
    base[(size_t)(e + 2) * 512 + d] = sg * a.z;
    base[(size_t)(e + 3) * 512 + d] = sg * a.w;
  }
}

// ---------------------------------------------------------------------------
// Zero-workspace f32 fallback (ws too small). Safe, slow.
// ---------------------------------------------------------------------------
__global__ __launch_bounds__(256)
void k_fallback(const float* __restrict__ R, const float* __restrict__ I,
                const float* __restrict__ W, float* __restrict__ out) {
  __shared__ float Rd[64][32], Id[64][32], Re[64][32], Ie[64][32];
  const int blk = blockIdx.x;
  const int et = blk & 15, dt = (blk >> 4) & 15, b = blk >> 8;
  const int d0 = dt * 32, e0 = et * 32;
  const int t = threadIdx.x;
  const int dd = t >> 3;
  const int ee0 = (t & 7) * 4;
  float ar[4] = {0,0,0,0}, ai[4] = {0,0,0,0};
  for (int s0 = 0; s0 < NS; s0 += 64) {
#pragma unroll
    for (int k = 0; k < 8; ++k) {
      const int idx = t + k * 256;
      const int row = idx >> 5, col = idx & 31;
      const float sw = sqrtf(W[b * NS + s0 + row]);
      const size_t gr = (size_t)(b * NS + s0 + row) * ND;
      Rd[row][col] = R[gr + d0 + col] * sw;
      Id[row][col] = I[gr + d0 + col] * sw;
      Re[row][col] = R[gr + e0 + col] * sw;
      Ie[row][col] = I[gr + e0 + col] * sw;
    }
    __syncthreads();
    for (int s = 0; s < 64; ++s) {
      const float rd = Rd[s][dd], id = Id[s][dd];
#pragma unroll
      for (int jx = 0; jx < 4; ++jx) {
        const float re = Re[s][ee0 + jx], ie = Ie[s][ee0 + jx];
        ar[jx] += rd * re + id * ie;
        ai[jx] += id * re - rd * ie;
      }
    }
    __syncthreads();
  }
  const size_t ob = (size_t)b * 262144;
#pragma unroll
  for (int jx = 0; jx < 4; ++jx) {
    out[          ob + (size_t)(d0 + dd) * 512 + e0 + ee0 + jx] = ar[jx];
    out[1048576 + ob + (size_t)(d0 + dd) * 512 + e0 + ee0 + jx] = ai[jx];
  }
}

extern "C" void kernel_launch(void* const* d_in, const int* in_sizes, int n_in,
                              void* d_out, int out_size, void* d_ws, size_t ws_size,
                              hipStream_t stream) {
  const float* R = (const float*)d_in[0];
  const float* I = (const float*)d_in[1];
  const float* W = (const float*)d_in[2];
  float* out = (float*)d_out;
  const size_t ytBytes   = (size_t)NB * NP * NS * 2;        // 64 MiB
  const size_t partBytes = (size_t)552 * 32768 * 4;         // 72.4 MB

  if (ws_size < ytBytes + partBytes) {
    k_fallback<<<dim3(NB * 16 * 16), dim3(256), 0, stream>>>(R, I, W, out);
    return;
  }

  unsigned short* Yt = (unsigned short*)d_ws;
  float* part = (float*)((char*)d_ws + ytBytes);

  k_prep<<<dim3(NB * 16 * 64), dim3(256), 0, stream>>>(R, I, W, Yt);
  k_gemm<<<dim3(512), dim3(512), 0, stream>>>(Yt, part);
  k_reduce<<<dim3(1280), dim3(256), 0, stream>>>(part, out);
}